// Round 1
// baseline (1058.066 us; speedup 1.0000x reference)
//
#include <hip/hip_runtime.h>
#include <hip/hip_bf16.h>
#include <math.h>

#define H 256
#define EDIM 6
#define NEG 0.2f
#define LN_EPS 1e-5f

// ---------------------------------------------------------------------------
// CSR build: degree histogram + loop_attr sums
// ---------------------------------------------------------------------------
__global__ void k_edge_hist(const int* __restrict__ ei, const float* __restrict__ eattr,
                            int* __restrict__ deg, float* __restrict__ loop_sum, int E) {
    int e = blockIdx.x * blockDim.x + threadIdx.x;
    if (e >= E) return;
    int dst = ei[E + e];
    atomicAdd(&deg[dst], 1);
#pragma unroll
    for (int k = 0; k < EDIM; k++)
        atomicAdd(&loop_sum[dst * EDIM + k], eattr[e * EDIM + k]);
}

// Single-block exclusive scan of deg -> row_ptr (and cursor copy). N ~ 20000.
__global__ void k_scan(const int* __restrict__ deg, int* __restrict__ row_ptr,
                       int* __restrict__ cursor, int N, int E) {
    __shared__ int wsum[16];
    __shared__ int wpre[16];
    __shared__ int s_carry;
    int tid = threadIdx.x;
    int lane = tid & 63, wv = tid >> 6;
    if (tid == 0) s_carry = 0;
    __syncthreads();
    for (int base = 0; base < N; base += 1024) {
        int i = base + tid;
        int v = (i < N) ? deg[i] : 0;
        int x = v;
#pragma unroll
        for (int d = 1; d < 64; d <<= 1) {
            int y = __shfl_up(x, d);
            if (lane >= d) x += y;
        }
        if (lane == 63) wsum[wv] = x;
        __syncthreads();
        int total = 0;
        if (tid == 0) {
            int a = 0;
            for (int w = 0; w < 16; w++) { wpre[w] = a; a += wsum[w]; }
            total = a;
        }
        __syncthreads();
        int excl = s_carry + wpre[wv] + (x - v);
        if (i < N) { row_ptr[i] = excl; cursor[i] = excl; }
        __syncthreads();
        if (tid == 0) s_carry += total;
        __syncthreads();
    }
    if (tid == 0) row_ptr[N] = E;
}

__global__ void k_loop_attr(float* __restrict__ loop_sum, const int* __restrict__ deg, int N) {
    int i = blockIdx.x * blockDim.x + threadIdx.x;
    if (i >= N * EDIM) return;
    float d = fmaxf((float)deg[i / EDIM], 1.0f);
    loop_sum[i] = loop_sum[i] / d;  // in place -> loop_attr
}

__global__ void k_scatter(const int* __restrict__ ei, const float* __restrict__ eattr,
                          int* __restrict__ cursor, int* __restrict__ src_sorted,
                          float* __restrict__ ea_sorted, int E) {
    int e = blockIdx.x * blockDim.x + threadIdx.x;
    if (e >= E) return;
    int s = ei[e], d = ei[E + e];
    int pos = atomicAdd(&cursor[d], 1);
    src_sorted[pos] = s;
#pragma unroll
    for (int k = 0; k < EDIM; k++)
        ea_sorted[pos * EDIM + k] = eattr[e * EDIM + k];
}

// ---------------------------------------------------------------------------
// Dual GEMM: C1 = A@W1 + b1, C2 = A@W2 + b2.  A: N x K row-major, W: K x 256.
// Tile 128x128, 256 threads, 8x8 micro-tile. blockIdx.x: [mat:1][ctile:1].
// ---------------------------------------------------------------------------
__global__ __launch_bounds__(256) void k_gemm(
    const float* __restrict__ A, int K, int N,
    const float* __restrict__ W1, const float* __restrict__ b1, float* __restrict__ C1,
    const float* __restrict__ W2, const float* __restrict__ b2, float* __restrict__ C2) {
    __shared__ float As[16][132];   // transposed A tile: As[kk][r], padded stride
    __shared__ float Bs[16][128];
    int tid = threadIdx.x;
    int tx = tid & 15, ty = tid >> 4;
    int mat = blockIdx.x >> 1;
    int c0 = (blockIdx.x & 1) * 128;
    int r0 = blockIdx.y * 128;
    const float* W = mat ? W2 : W1;
    const float* bv = mat ? b2 : b1;
    float* C = mat ? C2 : C1;

    float acc[8][8];
#pragma unroll
    for (int i = 0; i < 8; i++)
#pragma unroll
        for (int j = 0; j < 8; j++) acc[i][j] = 0.f;

    for (int k0 = 0; k0 < K; k0 += 16) {
        {   // stage A: 128 rows x 16 k  (transposed into As)
            int kk = tid & 15, rb = tid >> 4;
#pragma unroll
            for (int p = 0; p < 8; p++) {
                int r = rb + p * 16;
                int gr = r0 + r, gk = k0 + kk;
                float v = 0.f;
                if (gr < N && gk < K) v = A[gr * K + gk];
                As[kk][r] = v;
            }
        }
        {   // stage B: 16 k x 128 cols
            int c = tid & 127, kb = tid >> 7;
#pragma unroll
            for (int p = 0; p < 8; p++) {
                int kk = kb + p * 2;
                int gk = k0 + kk;
                float v = 0.f;
                if (gk < K) v = W[gk * H + c0 + c];
                Bs[kk][c] = v;
            }
        }
        __syncthreads();
#pragma unroll
        for (int kk = 0; kk < 16; kk++) {
            float a[8], b[8];
#pragma unroll
            for (int i = 0; i < 8; i++) a[i] = As[kk][ty * 8 + i];
#pragma unroll
            for (int j = 0; j < 8; j++) b[j] = Bs[kk][tx * 8 + j];
#pragma unroll
            for (int i = 0; i < 8; i++)
#pragma unroll
                for (int j = 0; j < 8; j++)
                    acc[i][j] = fmaf(a[i], b[j], acc[i][j]);
        }
        __syncthreads();
    }
#pragma unroll
    for (int i = 0; i < 8; i++) {
        int gr = r0 + ty * 8 + i;
        if (gr >= N) continue;
#pragma unroll
        for (int j = 0; j < 8; j += 4) {
            int gc = c0 + tx * 8 + j;
            float4 v;
            v.x = acc[i][j + 0] + bv[gc + 0];
            v.y = acc[i][j + 1] + bv[gc + 1];
            v.z = acc[i][j + 2] + bv[gc + 2];
            v.w = acc[i][j + 3] + bv[gc + 3];
            *(float4*)&C[gr * H + gc] = v;
        }
    }
}

// ---------------------------------------------------------------------------
// Fused GATv2 edge pass: one wave per node. Online segment-softmax +
// weighted aggregation + bias + LayerNorm + ReLU.
// Lane l owns channels 4l..4l+3.
// ---------------------------------------------------------------------------
__global__ __launch_bounds__(256) void k_gat(
    const float* __restrict__ hl, const float* __restrict__ hr,
    const int* __restrict__ row_ptr, const int* __restrict__ src_sorted,
    const float* __restrict__ ea_sorted, const float* __restrict__ loop_attr,
    const float* __restrict__ We, const float* __restrict__ attv,
    const float* __restrict__ bias, const float* __restrict__ lnw,
    const float* __restrict__ lnb, float* __restrict__ hout, int N) {
    int wv = threadIdx.x >> 6;
    int lane = threadIdx.x & 63;
    int node = blockIdx.x * 4 + wv;
    if (node >= N) return;
    int cb = lane * 4;

    float we[EDIM][4];
#pragma unroll
    for (int k = 0; k < EDIM; k++) {
        float4 t = *(const float4*)&We[k * H + cb];
        we[k][0] = t.x; we[k][1] = t.y; we[k][2] = t.z; we[k][3] = t.w;
    }
    float4 t;
    t = *(const float4*)&attv[cb];
    float av[4] = {t.x, t.y, t.z, t.w};
    t = *(const float4*)&hr[node * H + cb];
    float hrd[4] = {t.x, t.y, t.z, t.w};
    t = *(const float4*)&hl[node * H + cb];
    float hli[4] = {t.x, t.y, t.z, t.w};

    // --- self loop (always present) initializes online softmax ---
    float eav = (lane < EDIM) ? loop_attr[node * EDIM + lane] : 0.f;
    float ea[EDIM];
#pragma unroll
    for (int k = 0; k < EDIM; k++) ea[k] = __shfl(eav, k);

    float p = 0.f;
#pragma unroll
    for (int j = 0; j < 4; j++) {
        float v = hli[j] + hrd[j];
#pragma unroll
        for (int k = 0; k < EDIM; k++) v = fmaf(ea[k], we[k][j], v);
        v = (v > 0.f) ? v : NEG * v;
        p = fmaf(v, av[j], p);
    }
#pragma unroll
    for (int d = 1; d < 64; d <<= 1) p += __shfl_xor(p, d);

    float mmax = p;
    float denom = 1.f;
    float acc[4] = {hli[0], hli[1], hli[2], hli[3]};

    int e0 = row_ptr[node], e1 = row_ptr[node + 1];
    for (int e = e0; e < e1; e++) {
        int src = src_sorted[e];
        float eav2 = (lane < EDIM) ? ea_sorted[e * EDIM + lane] : 0.f;
        float ea2[EDIM];
#pragma unroll
        for (int k = 0; k < EDIM; k++) ea2[k] = __shfl(eav2, k);
        float4 h4 = *(const float4*)&hl[src * H + cb];
        float hs[4] = {h4.x, h4.y, h4.z, h4.w};
        float pp = 0.f;
#pragma unroll
        for (int j = 0; j < 4; j++) {
            float v = hs[j] + hrd[j];
#pragma unroll
            for (int k = 0; k < EDIM; k++) v = fmaf(ea2[k], we[k][j], v);
            v = (v > 0.f) ? v : NEG * v;
            pp = fmaf(v, av[j], pp);
        }
#pragma unroll
        for (int d = 1; d < 64; d <<= 1) pp += __shfl_xor(pp, d);

        float nm = fmaxf(mmax, pp);
        float scale = __expf(mmax - nm);
        float w = __expf(pp - nm);
        denom = denom * scale + w;
#pragma unroll
        for (int j = 0; j < 4; j++) acc[j] = fmaf(acc[j], scale, w * hs[j]) ;
        mmax = nm;
    }

    float inv = 1.f / denom;
    t = *(const float4*)&bias[cb];
    float o[4];
    o[0] = acc[0] * inv + t.x;
    o[1] = acc[1] * inv + t.y;
    o[2] = acc[2] * inv + t.z;
    o[3] = acc[3] * inv + t.w;

    // LayerNorm over 256 channels (wave-wide)
    float s = o[0] + o[1] + o[2] + o[3];
#pragma unroll
    for (int d = 1; d < 64; d <<= 1) s += __shfl_xor(s, d);
    float mu = s * (1.f / 256.f);
    float vs = 0.f;
#pragma unroll
    for (int j = 0; j < 4; j++) { float dd = o[j] - mu; vs += dd * dd; }
#pragma unroll
    for (int d = 1; d < 64; d <<= 1) vs += __shfl_xor(vs, d);
    float rstd = rsqrtf(vs * (1.f / 256.f) + LN_EPS);

    float4 w4 = *(const float4*)&lnw[cb];
    float4 b4 = *(const float4*)&lnb[cb];
    float lw[4] = {w4.x, w4.y, w4.z, w4.w};
    float lb[4] = {b4.x, b4.y, b4.z, b4.w};
    float4 outv;
    float* op = (float*)&outv;
#pragma unroll
    for (int j = 0; j < 4; j++) {
        float y = (o[j] - mu) * rstd * lw[j] + lb[j];
        op[j] = fmaxf(y, 0.f);
    }
    *(float4*)&hout[node * H + cb] = outv;
}

// ---------------------------------------------------------------------------
// Global mean pool per graph (batch sorted): one block per graph.
// ---------------------------------------------------------------------------
__global__ __launch_bounds__(256) void k_pool(const float* __restrict__ hf,
                                              const int* __restrict__ batch,
                                              float* __restrict__ out, int N) {
    __shared__ int s_lo, s_hi;
    int g = blockIdx.x, c = threadIdx.x;
    if (c == 0) {
        int lo = 0, hi = N;
        while (lo < hi) { int mid = (lo + hi) >> 1; if (batch[mid] < g) lo = mid + 1; else hi = mid; }
        s_lo = lo;
    }
    if (c == 1) {
        int lo = 0, hi = N;
        while (lo < hi) { int mid = (lo + hi) >> 1; if (batch[mid] < g + 1) lo = mid + 1; else hi = mid; }
        s_hi = lo;
    }
    __syncthreads();
    int lo = s_lo, hi = s_hi;
    float s = 0.f;
    for (int n = lo; n < hi; n++) s += hf[n * H + c];
    float cnt = fmaxf((float)(hi - lo), 1.f);
    out[g * H + c] = s / cnt;
}

// ---------------------------------------------------------------------------
extern "C" void kernel_launch(void* const* d_in, const int* in_sizes, int n_in,
                              void* d_out, int out_size, void* d_ws, size_t ws_size,
                              hipStream_t stream) {
    const float* x        = (const float*)d_in[0];
    const int*   ei       = (const int*)d_in[1];
    const float* eattr    = (const float*)d_in[2];
    const int*   batch    = (const int*)d_in[3];
    const float* W_l0     = (const float*)d_in[4];
    const float* W_r0     = (const float*)d_in[5];
    const float* W_l      = (const float*)d_in[6];
    const float* W_r      = (const float*)d_in[7];
    const float* b_l      = (const float*)d_in[8];
    const float* b_r      = (const float*)d_in[9];
    const float* W_e      = (const float*)d_in[10];
    const float* att      = (const float*)d_in[11];
    const float* bias     = (const float*)d_in[12];
    const float* ln_w     = (const float*)d_in[13];
    const float* ln_b     = (const float*)d_in[14];
    const float* lin_W    = (const float*)d_in[15];
    const float* lin_b    = (const float*)d_in[16];

    const int IN_DIM = 23;
    const int N = in_sizes[0] / IN_DIM;      // 20000
    const int E = in_sizes[1] / 2;           // 320000
    const int G = out_size / H;              // 64
    const int L = 4;

    // workspace layout (floats)
    float* fws = (float*)d_ws;
    float* h        = fws;                       // N*H
    float* hl       = h  + (size_t)N * H;        // N*H
    float* hr       = hl + (size_t)N * H;        // N*H
    float* loop_att = hr + (size_t)N * H;        // N*EDIM (sums then attrs)
    float* ea_sort  = loop_att + (size_t)N * EDIM; // E*EDIM
    int*   iws      = (int*)(ea_sort + (size_t)E * EDIM);
    int*   deg      = iws;                       // N
    int*   row_ptr  = deg + N;                   // N+1
    int*   cursor   = row_ptr + N + 1;           // N
    int*   src_sort = cursor + N;                // E

    hipMemsetAsync(deg, 0, (size_t)N * sizeof(int), stream);
    hipMemsetAsync(loop_att, 0, (size_t)N * EDIM * sizeof(float), stream);

    int tb = 256;
    k_edge_hist<<<(E + tb - 1) / tb, tb, 0, stream>>>(ei, eattr, deg, loop_att, E);
    k_scan<<<1, 1024, 0, stream>>>(deg, row_ptr, cursor, N, E);
    k_loop_attr<<<(N * EDIM + tb - 1) / tb, tb, 0, stream>>>(loop_att, deg, N);
    k_scatter<<<(E + tb - 1) / tb, tb, 0, stream>>>(ei, eattr, cursor, src_sort, ea_sort, E);

    int row_tiles = (N + 127) / 128;
    dim3 gdual(4, row_tiles), gsingle(2, row_tiles), blk(256);

    for (int l = 0; l < L; l++) {
        const float* A  = (l == 0) ? x : h;
        int K           = (l == 0) ? IN_DIM : H;
        const float* Wl = (l == 0) ? W_l0 : (W_l + (size_t)(l - 1) * H * H);
        const float* Wr = (l == 0) ? W_r0 : (W_r + (size_t)(l - 1) * H * H);
        k_gemm<<<gdual, blk, 0, stream>>>(A, K, N, Wl, b_l + l * H, hl, Wr, b_r + l * H, hr);
        k_gat<<<(N + 3) / 4, 256, 0, stream>>>(hl, hr, row_ptr, src_sort, ea_sort, loop_att,
                                               W_e + (size_t)l * EDIM * H, att + l * H,
                                               bias + l * H, ln_w + l * H, ln_b + l * H, h, N);
    }

    // final projection (single GEMM) -> reuse hl as h_final
    k_gemm<<<gsingle, blk, 0, stream>>>(h, H, N, lin_W, lin_b, hl, nullptr, nullptr, nullptr);
    k_pool<<<G, 256, 0, stream>>>(hl, batch, (float*)d_out, N);
}

// Round 2
// 743.493 us; speedup vs baseline: 1.4231x; 1.4231x over previous
//
#include <hip/hip_runtime.h>
#include <hip/hip_bf16.h>
#include <math.h>

#define H 256
#define EDIM 6
#define NEG 0.2f
#define LN_EPS 1e-5f
#define NPAD 20096   // 157 * 128

typedef __bf16 bf16x8 __attribute__((ext_vector_type(8)));
typedef float  floatx4 __attribute__((ext_vector_type(4)));

// ---------------------------------------------------------------------------
// CSR build: degree histogram only (loop_attr mean computed inside k_gat)
// ---------------------------------------------------------------------------
__global__ void k_edge_hist(const int* __restrict__ ei, int* __restrict__ deg, int E) {
    int e = blockIdx.x * blockDim.x + threadIdx.x;
    if (e >= E) return;
    atomicAdd(&deg[ei[E + e]], 1);
}

// Single-block exclusive scan of deg -> row_ptr (and cursor copy). N ~ 20000.
__global__ void k_scan(const int* __restrict__ deg, int* __restrict__ row_ptr,
                       int* __restrict__ cursor, int N, int E) {
    __shared__ int wsum[16];
    __shared__ int wpre[16];
    __shared__ int s_carry;
    int tid = threadIdx.x;
    int lane = tid & 63, wv = tid >> 6;
    if (tid == 0) s_carry = 0;
    __syncthreads();
    for (int base = 0; base < N; base += 1024) {
        int i = base + tid;
        int v = (i < N) ? deg[i] : 0;
        int x = v;
#pragma unroll
        for (int d = 1; d < 64; d <<= 1) {
            int y = __shfl_up(x, d);
            if (lane >= d) x += y;
        }
        if (lane == 63) wsum[wv] = x;
        __syncthreads();
        int total = 0;
        if (tid == 0) {
            int a = 0;
            for (int w = 0; w < 16; w++) { wpre[w] = a; a += wsum[w]; }
            total = a;
        }
        __syncthreads();
        int excl = s_carry + wpre[wv] + (x - v);
        if (i < N) { row_ptr[i] = excl; cursor[i] = excl; }
        __syncthreads();
        if (tid == 0) s_carry += total;
        __syncthreads();
    }
    if (tid == 0) row_ptr[N] = E;
}

__global__ void k_scatter(const int* __restrict__ ei, const float* __restrict__ eattr,
                          int* __restrict__ cursor, int* __restrict__ src_sorted,
                          float* __restrict__ ea_sorted, int E) {
    int e = blockIdx.x * blockDim.x + threadIdx.x;
    if (e >= E) return;
    int s = ei[e], d = ei[E + e];
    int pos = atomicAdd(&cursor[d], 1);
    src_sorted[pos] = s;
#pragma unroll
    for (int k = 0; k < EDIM; k++)
        ea_sorted[pos * EDIM + k] = eattr[e * EDIM + k];
}

// ---------------------------------------------------------------------------
// Weight conversions to transposed bf16 [c][k]
// ---------------------------------------------------------------------------
__global__ void k_conv_x(const float* __restrict__ x, __hip_bfloat16* __restrict__ xb, int N) {
    int idx = blockIdx.x * blockDim.x + threadIdx.x;
    if (idx >= NPAD * 32) return;
    int r = idx >> 5, k = idx & 31;
    float v = (r < N && k < 23) ? x[r * 23 + k] : 0.f;
    xb[idx] = __float2bfloat16(v);
}

__global__ void k_conv_w0(const float* __restrict__ Wl0, const float* __restrict__ Wr0,
                          __hip_bfloat16* __restrict__ out) {
    int idx = blockIdx.x * blockDim.x + threadIdx.x;
    if (idx >= 2 * 256 * 32) return;
    int mat = idx >> 13, rem = idx & 8191;
    int c = rem >> 5, k = rem & 31;
    const float* W = mat ? Wr0 : Wl0;
    float v = (k < 23) ? W[k * 256 + c] : 0.f;
    out[idx] = __float2bfloat16(v);
}

__global__ void k_conv_w(const float* __restrict__ Wl, const float* __restrict__ Wr,
                         const float* __restrict__ lin, __hip_bfloat16* __restrict__ out) {
    int idx = blockIdx.x * blockDim.x + threadIdx.x;
    if (idx >= 7 * 65536) return;
    int mat = idx >> 16, rem = idx & 65535;
    int c = rem >> 8, k = rem & 255;
    const float* W = (mat < 3) ? (Wl + (size_t)mat * 65536)
                   : (mat < 6) ? (Wr + (size_t)(mat - 3) * 65536)
                   : lin;
    out[idx] = __float2bfloat16(W[k * 256 + c]);
}

// ---------------------------------------------------------------------------
// MFMA dual GEMM: C = A@W + b for up to 2 weight matrices.
// A: NPAD x K bf16 row-major (K contiguous). Wt: 256 x K bf16 (transposed, K contig).
// Block 256 thr = 4 waves (2x2), tile 128x128, wave tile 64x64 = 4x4 MFMA 16x16x32.
// No LDS: fragments are contiguous 16B loads straight from global (L1/L2-cached).
// ---------------------------------------------------------------------------
__global__ __launch_bounds__(256) void k_gemm_mfma(
    const __hip_bfloat16* __restrict__ A, int K, int N,
    const __hip_bfloat16* __restrict__ Wt1, const float* __restrict__ b1, float* __restrict__ C1,
    const __hip_bfloat16* __restrict__ Wt2, const float* __restrict__ b2, float* __restrict__ C2) {
    int tid = threadIdx.x;
    int wv = tid >> 6, lane = tid & 63;
    int quad = lane >> 4, l16 = lane & 15;
    int mat = blockIdx.x >> 1;
    int c0 = (blockIdx.x & 1) * 128;
    int r0 = blockIdx.y * 128;
    const __hip_bfloat16* Wt = mat ? Wt2 : Wt1;
    const float* bv = mat ? b2 : b1;
    float* C = mat ? C2 : C1;
    int wm = wv >> 1, wn = wv & 1;
    int rbase = r0 + wm * 64;
    int cbase = c0 + wn * 64;

    floatx4 acc[4][4] = {};
    const __bf16* Ab = (const __bf16*)A;
    const __bf16* Bb = (const __bf16*)Wt;
    for (int k0 = 0; k0 < K; k0 += 32) {
        bf16x8 a[4], b[4];
        const __bf16* Ap = Ab + (size_t)(rbase + l16) * K + k0 + quad * 8;
#pragma unroll
        for (int mi = 0; mi < 4; mi++)
            a[mi] = *(const bf16x8*)(Ap + (size_t)mi * 16 * K);
        const __bf16* Bp = Bb + (size_t)(cbase + l16) * K + k0 + quad * 8;
#pragma unroll
        for (int ni = 0; ni < 4; ni++)
            b[ni] = *(const bf16x8*)(Bp + (size_t)ni * 16 * K);
#pragma unroll
        for (int mi = 0; mi < 4; mi++)
#pragma unroll
            for (int ni = 0; ni < 4; ni++)
                acc[mi][ni] = __builtin_amdgcn_mfma_f32_16x16x32_bf16(a[mi], b[ni], acc[mi][ni], 0, 0, 0);
    }
#pragma unroll
    for (int ni = 0; ni < 4; ni++) {
        int c = cbase + ni * 16 + l16;
        float bb = bv[c];
#pragma unroll
        for (int mi = 0; mi < 4; mi++) {
#pragma unroll
            for (int r = 0; r < 4; r++) {
                int gr = rbase + mi * 16 + quad * 4 + r;
                if (gr < N) C[(size_t)gr * H + c] = acc[mi][ni][r] + bb;
            }
        }
    }
}

// ---------------------------------------------------------------------------
// Fused GATv2 edge pass: one wave per node. Online segment-softmax +
// aggregation + bias + LayerNorm + ReLU. Self loop handled LAST using the
// running mean of incoming edge attrs (== reference's fill_value='mean').
// Lane l owns channels 4l..4l+3. Output written as bf16 (feeds next GEMM).
// ---------------------------------------------------------------------------
struct bh4 { __hip_bfloat16 a, b, c, d; };

__global__ __launch_bounds__(256) void k_gat(
    const float* __restrict__ hl, const float* __restrict__ hr,
    const int* __restrict__ row_ptr, const int* __restrict__ src_sorted,
    const float* __restrict__ ea_sorted,
    const float* __restrict__ We, const float* __restrict__ attv,
    const float* __restrict__ bias, const float* __restrict__ lnw,
    const float* __restrict__ lnb, __hip_bfloat16* __restrict__ hout, int N) {
    int wv = threadIdx.x >> 6;
    int lane = threadIdx.x & 63;
    int node = blockIdx.x * 4 + wv;
    if (node >= N) return;
    int cb = lane * 4;

    float we[EDIM][4];
#pragma unroll
    for (int k = 0; k < EDIM; k++) {
        float4 t = *(const float4*)&We[k * H + cb];
        we[k][0] = t.x; we[k][1] = t.y; we[k][2] = t.z; we[k][3] = t.w;
    }
    float4 t;
    t = *(const float4*)&attv[cb];
    float av[4] = {t.x, t.y, t.z, t.w};
    t = *(const float4*)&hr[node * H + cb];
    float hrd[4] = {t.x, t.y, t.z, t.w};
    t = *(const float4*)&hl[node * H + cb];
    float hli[4] = {t.x, t.y, t.z, t.w};

    float mmax = -INFINITY;
    float denom = 0.f;
    float acc[4] = {0.f, 0.f, 0.f, 0.f};
    float easum = 0.f;

    int e0 = row_ptr[node], e1 = row_ptr[node + 1];
    for (int e = e0; e < e1; e++) {
        int src = src_sorted[e];
        float eav2 = (lane < EDIM) ? ea_sorted[e * EDIM + lane] : 0.f;
        easum += eav2;
        float ea2[EDIM];
#pragma unroll
        for (int k = 0; k < EDIM; k++) ea2[k] = __shfl(eav2, k);
        float4 h4 = *(const float4*)&hl[src * H + cb];
        float hs[4] = {h4.x, h4.y, h4.z, h4.w};
        float pp = 0.f;
#pragma unroll
        for (int j = 0; j < 4; j++) {
            float v = hs[j] + hrd[j];
#pragma unroll
            for (int k = 0; k < EDIM; k++) v = fmaf(ea2[k], we[k][j], v);
            v = (v > 0.f) ? v : NEG * v;
            pp = fmaf(v, av[j], pp);
        }
#pragma unroll
        for (int d = 1; d < 64; d <<= 1) pp += __shfl_xor(pp, d);

        float nm = fmaxf(mmax, pp);
        float scale = __expf(mmax - nm);
        float w = __expf(pp - nm);
        denom = denom * scale + w;
#pragma unroll
        for (int j = 0; j < 4; j++) acc[j] = fmaf(acc[j], scale, w * hs[j]);
        mmax = nm;
    }

    // self loop: edge_attr = mean of incoming attrs
    {
        float degf = (float)(e1 - e0);
        float eamean = easum / fmaxf(degf, 1.f);
        float ea[EDIM];
#pragma unroll
        for (int k = 0; k < EDIM; k++) ea[k] = __shfl(eamean, k);
        float p = 0.f;
#pragma unroll
        for (int j = 0; j < 4; j++) {
            float v = hli[j] + hrd[j];
#pragma unroll
            for (int k = 0; k < EDIM; k++) v = fmaf(ea[k], we[k][j], v);
            v = (v > 0.f) ? v : NEG * v;
            p = fmaf(v, av[j], p);
        }
#pragma unroll
        for (int d = 1; d < 64; d <<= 1) p += __shfl_xor(p, d);
        float nm = fmaxf(mmax, p);
        float scale = __expf(mmax - nm);
        float w = __expf(p - nm);
        denom = denom * scale + w;
#pragma unroll
        for (int j = 0; j < 4; j++) acc[j] = fmaf(acc[j], scale, w * hli[j]);
    }

    float inv = 1.f / denom;
    t = *(const float4*)&bias[cb];
    float o[4];
    o[0] = acc[0] * inv + t.x;
    o[1] = acc[1] * inv + t.y;
    o[2] = acc[2] * inv + t.z;
    o[3] = acc[3] * inv + t.w;

    // LayerNorm over 256 channels (wave-wide)
    float s = o[0] + o[1] + o[2] + o[3];
#pragma unroll
    for (int d = 1; d < 64; d <<= 1) s += __shfl_xor(s, d);
    float mu = s * (1.f / 256.f);
    float vs = 0.f;
#pragma unroll
    for (int j = 0; j < 4; j++) { float dd = o[j] - mu; vs += dd * dd; }
#pragma unroll
    for (int d = 1; d < 64; d <<= 1) vs += __shfl_xor(vs, d);
    float rstd = rsqrtf(vs * (1.f / 256.f) + LN_EPS);

    float4 w4 = *(const float4*)&lnw[cb];
    float4 b4 = *(const float4*)&lnb[cb];
    bh4 outv;
    float y0 = fmaxf((o[0] - mu) * rstd * w4.x + b4.x, 0.f);
    float y1 = fmaxf((o[1] - mu) * rstd * w4.y + b4.y, 0.f);
    float y2 = fmaxf((o[2] - mu) * rstd * w4.z + b4.z, 0.f);
    float y3 = fmaxf((o[3] - mu) * rstd * w4.w + b4.w, 0.f);
    outv.a = __float2bfloat16(y0);
    outv.b = __float2bfloat16(y1);
    outv.c = __float2bfloat16(y2);
    outv.d = __float2bfloat16(y3);
    *(bh4*)&hout[(size_t)node * H + cb] = outv;
}

// ---------------------------------------------------------------------------
// Global mean pool per graph (batch sorted): one block per graph.
// ---------------------------------------------------------------------------
__global__ __launch_bounds__(256) void k_pool(const float* __restrict__ hf,
                                              const int* __restrict__ batch,
                                              float* __restrict__ out, int N) {
    __shared__ int s_lo, s_hi;
    int g = blockIdx.x, c = threadIdx.x;
    if (c == 0) {
        int lo = 0, hi = N;
        while (lo < hi) { int mid = (lo + hi) >> 1; if (batch[mid] < g) lo = mid + 1; else hi = mid; }
        s_lo = lo;
    }
    if (c == 1) {
        int lo = 0, hi = N;
        while (lo < hi) { int mid = (lo + hi) >> 1; if (batch[mid] < g + 1) lo = mid + 1; else hi = mid; }
        s_hi = lo;
    }
    __syncthreads();
    int lo = s_lo, hi = s_hi;
    float s = 0.f;
    for (int n = lo; n < hi; n++) s += hf[n * H + c];
    float cnt = fmaxf((float)(hi - lo), 1.f);
    out[g * H + c] = s / cnt;
}

// ---------------------------------------------------------------------------
extern "C" void kernel_launch(void* const* d_in, const int* in_sizes, int n_in,
                              void* d_out, int out_size, void* d_ws, size_t ws_size,
                              hipStream_t stream) {
    const float* x        = (const float*)d_in[0];
    const int*   ei       = (const int*)d_in[1];
    const float* eattr    = (const float*)d_in[2];
    const int*   batch    = (const int*)d_in[3];
    const float* W_l0     = (const float*)d_in[4];
    const float* W_r0     = (const float*)d_in[5];
    const float* W_l      = (const float*)d_in[6];
    const float* W_r      = (const float*)d_in[7];
    const float* b_l      = (const float*)d_in[8];
    const float* b_r      = (const float*)d_in[9];
    const float* W_e      = (const float*)d_in[10];
    const float* att      = (const float*)d_in[11];
    const float* bias     = (const float*)d_in[12];
    const float* ln_w     = (const float*)d_in[13];
    const float* ln_b     = (const float*)d_in[14];
    const float* lin_W    = (const float*)d_in[15];
    const float* lin_b    = (const float*)d_in[16];

    const int IN_DIM = 23;
    const int N = in_sizes[0] / IN_DIM;      // 20000
    const int E = in_sizes[1] / 2;           // 320000
    const int G = out_size / H;              // 64
    const int L = 4;

    // workspace layout
    char* p = (char*)d_ws;
    float* hl = (float*)p;               p += (size_t)N * H * 4;
    float* hr = (float*)p;               p += (size_t)N * H * 4;
    float* ea_sort = (float*)p;          p += (size_t)E * EDIM * 4;
    __hip_bfloat16* hb  = (__hip_bfloat16*)p; p += (size_t)NPAD * H * 2;
    __hip_bfloat16* xb  = (__hip_bfloat16*)p; p += (size_t)NPAD * 32 * 2;
    __hip_bfloat16* w0t = (__hip_bfloat16*)p; p += (size_t)2 * 256 * 32 * 2;   // Wl0t | Wr0t
    __hip_bfloat16* wbig = (__hip_bfloat16*)p; p += (size_t)7 * 65536 * 2;     // Wlt[3] | Wrt[3] | linWt
    int* deg      = (int*)p;             p += (size_t)N * 4;
    int* row_ptr  = (int*)p;             p += (size_t)(N + 1) * 4;
    int* cursor   = (int*)p;             p += (size_t)N * 4;
    int* src_sort = (int*)p;             p += (size_t)E * 4;

    __hip_bfloat16* Wl0t = w0t;
    __hip_bfloat16* Wr0t = w0t + 8192;
    __hip_bfloat16* Wlt  = wbig;
    __hip_bfloat16* Wrt  = wbig + (size_t)3 * 65536;
    __hip_bfloat16* linWt = wbig + (size_t)6 * 65536;

    hipMemsetAsync(deg, 0, (size_t)N * sizeof(int), stream);
    // zero pad rows of hb (rows N..NPAD) so GEMM reads of the pad region are 0
    hipMemsetAsync(hb + (size_t)N * H, 0, (size_t)(NPAD - N) * H * 2, stream);

    int tb = 256;
    k_conv_x<<<(NPAD * 32 + tb - 1) / tb, tb, 0, stream>>>(x, xb, N);
    k_conv_w0<<<(2 * 256 * 32 + tb - 1) / tb, tb, 0, stream>>>(W_l0, W_r0, w0t);
    k_conv_w<<<(7 * 65536 + tb - 1) / tb, tb, 0, stream>>>(W_l, W_r, lin_W, wbig);

    k_edge_hist<<<(E + tb - 1) / tb, tb, 0, stream>>>(ei, deg, E);
    k_scan<<<1, 1024, 0, stream>>>(deg, row_ptr, cursor, N, E);
    k_scatter<<<(E + tb - 1) / tb, tb, 0, stream>>>(ei, eattr, cursor, src_sort, ea_sort, E);

    dim3 gdual(4, NPAD / 128), gsingle(2, NPAD / 128), blk(256);

    for (int l = 0; l < L; l++) {
        const __hip_bfloat16* A  = (l == 0) ? xb : hb;
        int K                    = (l == 0) ? 32 : H;
        const __hip_bfloat16* Wl = (l == 0) ? Wl0t : (Wlt + (size_t)(l - 1) * 65536);
        const __hip_bfloat16* Wr = (l == 0) ? Wr0t : (Wrt + (size_t)(l - 1) * 65536);
        k_gemm_mfma<<<gdual, blk, 0, stream>>>(A, K, N, Wl, b_l + l * H, hl, Wr, b_r + l * H, hr);
        k_gat<<<(N + 3) / 4, 256, 0, stream>>>(hl, hr, row_ptr, src_sort, ea_sort,
                                               W_e + (size_t)l * EDIM * H, att + l * H,
                                               bias + l * H, ln_w + l * H, ln_b + l * H, hb, N);
    }

    // final projection (single GEMM, fp32 out) -> hl, then pool
    k_gemm_mfma<<<gsingle, blk, 0, stream>>>(hb, H, N, linWt, lin_b, hl, nullptr, nullptr, nullptr);
    k_pool<<<G, 256, 0, stream>>>(hl, batch, (float*)d_out, N);
}